// Round 1
// baseline (6839.493 us; speedup 1.0000x reference)
//
#include <hip/hip_runtime.h>
#include <hip/hip_bf16.h>

#define STEP 0.01f
#define D 64
#define NUM_LAYERS 10

// ---------------- setup kernels ----------------

__global__ void k_init_nodes(const float* __restrict__ x,
                             float* __restrict__ u0, float* __restrict__ x0,
                             float* __restrict__ v0, float* __restrict__ deg, int N) {
    int i = blockIdx.x * blockDim.x + threadIdx.x;
    if (i < N * D) { u0[i] = x[i]; x0[i] = x[i]; }
    if (i < N)     { v0[i] = 1.0f; deg[i] = 1.0f; }
}

__global__ void k_deg(const int* __restrict__ ei, float* __restrict__ deg, int E) {
    int e = blockIdx.x * blockDim.x + threadIdx.x;
    if (e < E) unsafeAtomicAdd(&deg[ei[e]], 1.0f);   // src row of edge_index
}

__global__ void k_inv(float* __restrict__ deg, int N) {
    int n = blockIdx.x * blockDim.x + threadIdx.x;
    if (n < N) deg[n] = 1.0f / deg[n];
}

// y = 2*A@x + b   (one block of 256 per node; float4-coalesced A reads)
__global__ __launch_bounds__(256) void k_grad_init(
        const float* __restrict__ A, const float* __restrict__ b,
        const float* __restrict__ x, float* __restrict__ y, int N) {
    int n = blockIdx.x;
    int tid = threadIdx.x;
    int lane = tid & 63, w = tid >> 6;
    int colgrp = lane & 15;
    const float* An = A + (size_t)n * D * D;
    float4 xr = ((const float4*)(x + (size_t)n * D))[colgrp];
    int rbase = w * 16 + (lane >> 4);
#pragma unroll
    for (int g = 0; g < 4; ++g) {
        int row = rbase + g * 4;
        float4 a = ((const float4*)(An + (size_t)row * D))[colgrp];
        float p = a.x * xr.x + a.y * xr.y + a.z * xr.z + a.w * xr.w;
        p += __shfl_xor(p, 1);
        p += __shfl_xor(p, 2);
        p += __shfl_xor(p, 4);
        p += __shfl_xor(p, 8);
        if (colgrp == 0) y[(size_t)n * D + row] = 2.0f * p + b[(size_t)n * D + row];
    }
}

// ---------------- per-layer kernels ----------------

// self-loop terms of all three mixes (writes fully initialize un/yn/vn)
__global__ void k_layer_init(const float* __restrict__ u, const float* __restrict__ y,
                             const float* __restrict__ v, const float* __restrict__ invdeg,
                             float* __restrict__ un, float* __restrict__ yn,
                             float* __restrict__ vn, int N) {
    int i = blockIdx.x * blockDim.x + threadIdx.x;
    if (i >= N * D) return;
    int n = i >> 6;
    float w = invdeg[n];
    float yi = y[i];
    un[i] = (u[i] - STEP * yi) * w;
    yn[i] = yi * w;
    if ((i & 63) == 0) vn[n] = v[n] * w;
}

// edge scatter for all three mixes; thread = (edge, 4-feature group)
__global__ __launch_bounds__(256) void k_edges(
        const int* __restrict__ ei,
        const float* __restrict__ u, const float* __restrict__ y,
        const float* __restrict__ v, const float* __restrict__ invdeg,
        float* __restrict__ un, float* __restrict__ yn, float* __restrict__ vn, int E) {
    int t = blockIdx.x * blockDim.x + threadIdx.x;
    if (t >= E * 16) return;
    int e = t >> 4, q = t & 15;
    int s = ei[e];
    int d = ei[E + e];
    float w = invdeg[s];
    float4 u4 = ((const float4*)(u + (size_t)s * D))[q];
    float4 y4 = ((const float4*)(y + (size_t)s * D))[q];
    float* und = un + (size_t)d * D + q * 4;
    float* ynd = yn + (size_t)d * D + q * 4;
    unsafeAtomicAdd(und + 0, (u4.x - STEP * y4.x) * w);
    unsafeAtomicAdd(und + 1, (u4.y - STEP * y4.y) * w);
    unsafeAtomicAdd(und + 2, (u4.z - STEP * y4.z) * w);
    unsafeAtomicAdd(und + 3, (u4.w - STEP * y4.w) * w);
    unsafeAtomicAdd(ynd + 0, y4.x * w);
    unsafeAtomicAdd(ynd + 1, y4.y * w);
    unsafeAtomicAdd(ynd + 2, y4.z * w);
    unsafeAtomicAdd(ynd + 3, y4.w * w);
    if (q == 0) unsafeAtomicAdd(vn + d, v[s] * w);
}

// x1 = un/vn ; dx = x1 - x0 (in LDS) ; x0 = x1 ; yn += 2*A@dx
__global__ __launch_bounds__(256) void k_xmv(
        const float* __restrict__ A, const float* __restrict__ un,
        const float* __restrict__ vn, float* __restrict__ x0,
        float* __restrict__ yn, int N) {
    __shared__ __align__(16) float sdx[D];
    int n = blockIdx.x;
    int tid = threadIdx.x;
    if (tid < D) {
        float xv = un[(size_t)n * D + tid] / vn[n];
        sdx[tid] = xv - x0[(size_t)n * D + tid];
        x0[(size_t)n * D + tid] = xv;
    }
    __syncthreads();
    int lane = tid & 63, w = tid >> 6;
    int colgrp = lane & 15;
    float4 xr = ((const float4*)sdx)[colgrp];
    const float* An = A + (size_t)n * D * D;
    int rbase = w * 16 + (lane >> 4);
#pragma unroll
    for (int g = 0; g < 4; ++g) {
        int row = rbase + g * 4;
        float4 a = ((const float4*)(An + (size_t)row * D))[colgrp];
        float p = a.x * xr.x + a.y * xr.y + a.z * xr.z + a.w * xr.w;
        p += __shfl_xor(p, 1);
        p += __shfl_xor(p, 2);
        p += __shfl_xor(p, 4);
        p += __shfl_xor(p, 8);
        if (colgrp == 0) yn[(size_t)n * D + row] += 2.0f * p;
    }
}

__global__ void k_final(const float* __restrict__ x0, float* __restrict__ out,
                        int ND, int last_idx, float comm) {
    int i = blockIdx.x * blockDim.x + threadIdx.x;
    if (i < ND) out[i] = x0[i];
    if (i == 0) out[last_idx] = comm;
}

// ---------------- host launcher ----------------

extern "C" void kernel_launch(void* const* d_in, const int* in_sizes, int n_in,
                              void* d_out, int out_size, void* d_ws, size_t ws_size,
                              hipStream_t stream) {
    const float* A  = (const float*)d_in[0];
    const float* b  = (const float*)d_in[1];
    const float* x  = (const float*)d_in[2];
    const int*   ei = (const int*)d_in[3];

    const int N = in_sizes[1] / D;        // b is [N, D]
    const int E = in_sizes[3] / 2;        // edge_index is [2, E]
    const size_t ND = (size_t)N * D;

    float* ws = (float*)d_ws;
    float* u0 = ws;
    float* u1 = u0 + ND;
    float* y0 = u1 + ND;
    float* y1 = y0 + ND;
    float* x0 = y1 + ND;
    float* v0 = x0 + ND;
    float* v1 = v0 + N;
    float* invdeg = v1 + N;

    const int gND = (N * D + 255) / 256;

    k_init_nodes<<<gND, 256, 0, stream>>>(x, u0, x0, v0, invdeg, N);
    k_deg<<<(E + 255) / 256, 256, 0, stream>>>(ei, invdeg, E);
    k_inv<<<(N + 255) / 256, 256, 0, stream>>>(invdeg, N);
    k_grad_init<<<N, 256, 0, stream>>>(A, b, x, y0, N);

    float *uc = u0, *un = u1, *yc = y0, *yn = y1, *vc = v0, *vn = v1;
    for (int l = 0; l < NUM_LAYERS; ++l) {
        k_layer_init<<<gND, 256, 0, stream>>>(uc, yc, vc, invdeg, un, yn, vn, N);
        k_edges<<<(E * 16 + 255) / 256, 256, 0, stream>>>(ei, uc, yc, vc, invdeg, un, yn, vn, E);
        k_xmv<<<N, 256, 0, stream>>>(A, un, vn, x0, yn, N);
        float* t;
        t = uc; uc = un; un = t;
        t = yc; yc = yn; yn = t;
        t = vc; vc = vn; vn = t;
    }

    float comm = (float)(3 * NUM_LAYERS * E);
    k_final<<<gND, 256, 0, stream>>>(x0, (float*)d_out, (int)ND, out_size - 1, comm);
}

// Round 2
// 1503.442 us; speedup vs baseline: 4.5492x; 4.5492x over previous
//
#include <hip/hip_runtime.h>
#include <hip/hip_bf16.h>

#define STEP 0.01f
#define D 64
#define NUM_LAYERS 10

// ---------------- CSR build ----------------

__global__ void k_setup(float* __restrict__ degf, int* __restrict__ degd, int N) {
    int n = blockIdx.x * blockDim.x + threadIdx.x;
    if (n < N) { degf[n] = 1.0f; degd[n] = 0; }  // out-degree includes self-loop
}

__global__ void k_deg2(const int* __restrict__ ei, float* __restrict__ degf,
                       int* __restrict__ degd, int E) {
    int e = blockIdx.x * blockDim.x + threadIdx.x;
    if (e < E) {
        unsafeAtomicAdd(&degf[ei[e]], 1.0f);   // out-degree (src)
        atomicAdd(&degd[ei[E + e]], 1);        // in-degree (dst)
    }
}

// single-block scan: row_ptr/cursor from in-degree histogram; invdeg = 1/out-degree
__global__ __launch_bounds__(1024) void k_scan(
        const int* __restrict__ degd, const float* __restrict__ degf,
        int* __restrict__ row_ptr, int* __restrict__ cursor,
        float* __restrict__ invdeg, int N, int E) {
    __shared__ int part[1024];
    int tid = threadIdx.x;
    int chunk = (N + 1023) / 1024;
    int lo = tid * chunk, hi = min(lo + chunk, N);
    int s = 0;
    for (int i = lo; i < hi; ++i) s += degd[i];
    part[tid] = s;
    __syncthreads();
    for (int off = 1; off < 1024; off <<= 1) {
        int v = (tid >= off) ? part[tid - off] : 0;
        __syncthreads();
        part[tid] += v;
        __syncthreads();
    }
    int base = (tid == 0) ? 0 : part[tid - 1];
    for (int i = lo; i < hi; ++i) {
        row_ptr[i] = base;
        cursor[i] = base;
        base += degd[i];
        invdeg[i] = 1.0f / degf[i];
    }
    if (tid == 1023) row_ptr[N] = E;
}

__global__ void k_scatter(const int* __restrict__ ei, int* __restrict__ cursor,
                          int* __restrict__ col, int E) {
    int e = blockIdx.x * blockDim.x + threadIdx.x;
    if (e < E) {
        int pos = atomicAdd(&cursor[ei[E + e]], 1);
        col[pos] = ei[e];
    }
}

// ---------------- init: y=2Ax+b, emit pre-weighted uw/yw/vw, x0=x ----------------

__global__ __launch_bounds__(256) void k_init_grad(
        const float* __restrict__ A, const float* __restrict__ b,
        const float* __restrict__ x, const float* __restrict__ invdeg,
        float* __restrict__ uw, float* __restrict__ yw, float* __restrict__ vw,
        float* __restrict__ x0, int N) {
    __shared__ float syn[D];
    int n = blockIdx.x, tid = threadIdx.x;
    int lane = tid & 63, w = tid >> 6, colgrp = lane & 15;
    const float* An = A + (size_t)n * D * D;
    float4 xr = ((const float4*)(x + (size_t)n * D))[colgrp];
    int rbase = w * 16 + (lane >> 4);
#pragma unroll
    for (int g = 0; g < 4; ++g) {
        int row = rbase + g * 4;
        float4 a = ((const float4*)(An + (size_t)row * D))[colgrp];
        float p = a.x * xr.x + a.y * xr.y + a.z * xr.z + a.w * xr.w;
        p += __shfl_xor(p, 1);
        p += __shfl_xor(p, 2);
        p += __shfl_xor(p, 4);
        p += __shfl_xor(p, 8);
        if (colgrp == 0) syn[row] = 2.0f * p + b[(size_t)n * D + row];
    }
    __syncthreads();
    if (tid < D) {
        size_t off = (size_t)n * D + tid;
        float wd = invdeg[n];
        float xv = x[off];
        float yv = syn[tid];
        uw[off] = (xv - STEP * yv) * wd;
        yw[off] = yv * wd;
        x0[off] = xv;
        if (tid == 0) vw[n] = wd;   // v = 1 initially
    }
}

// ---------------- fused layer: gather + x1 + matvec + emit next pre-weighted ----------------

__global__ __launch_bounds__(256) void k_layer(
        const float* __restrict__ A,
        const int* __restrict__ row_ptr, const int* __restrict__ col,
        const float* __restrict__ uw, const float* __restrict__ yw,
        const float* __restrict__ vw, const float* __restrict__ invdeg,
        float* __restrict__ uwn, float* __restrict__ ywn, float* __restrict__ vwn,
        float* __restrict__ x0, int N) {
    __shared__ float su[4][D];
    __shared__ float sy[4][D];
    __shared__ float sv[4];
    __shared__ __align__(16) float sdx[D];
    __shared__ float sun[D];
    __shared__ float sytot[D];
    __shared__ float syn[D];
    __shared__ float svn;

    int n = blockIdx.x, tid = threadIdx.x;
    int lane = tid & 63, w = tid >> 6;

    // phase 1: gather incoming messages (no atomics, coalesced 256B row reads)
    int rs = row_ptr[n], re = row_ptr[n + 1];
    float au = 0.0f, ay = 0.0f, av = 0.0f;
    for (int e = rs + w; e < re; e += 4) {
        int s = col[e];
        size_t off = (size_t)s * D + lane;
        au += uw[off];
        ay += yw[off];
        if (lane == 0) av += vw[s];
    }
    su[w][lane] = au;
    sy[w][lane] = ay;
    if (lane == 0) sv[w] = av;
    __syncthreads();

    // phase 2: combine + self term; x1 = un/vn; dx = x1 - x0
    if (w == 0) {
        size_t off = (size_t)n * D + lane;
        float ut = su[0][lane] + su[1][lane] + su[2][lane] + su[3][lane] + uw[off];
        float yt = sy[0][lane] + sy[1][lane] + sy[2][lane] + sy[3][lane] + yw[off];
        float vt = sv[0] + sv[1] + sv[2] + sv[3] + vw[n];
        float x1 = ut / vt;
        sdx[lane] = x1 - x0[off];
        x0[off] = x1;
        sun[lane] = ut;
        sytot[lane] = yt;
        if (lane == 0) svn = vt;
    }
    __syncthreads();

    // phase 3: yn = yt + 2*A@dx   (g1-g0 folded into one matvec)
    int colgrp = lane & 15;
    float4 xr = ((const float4*)sdx)[colgrp];
    const float* An = A + (size_t)n * D * D;
    int rbase = w * 16 + (lane >> 4);
#pragma unroll
    for (int g = 0; g < 4; ++g) {
        int row = rbase + g * 4;
        float4 a = ((const float4*)(An + (size_t)row * D))[colgrp];
        float p = a.x * xr.x + a.y * xr.y + a.z * xr.z + a.w * xr.w;
        p += __shfl_xor(p, 1);
        p += __shfl_xor(p, 2);
        p += __shfl_xor(p, 4);
        p += __shfl_xor(p, 8);
        if (colgrp == 0) syn[row] = sytot[row] + 2.0f * p;
    }
    __syncthreads();

    // phase 4: emit next layer's pre-weighted messages
    if (tid < D) {
        float wd = invdeg[n];
        float ynf = syn[tid];
        size_t off = (size_t)n * D + tid;
        uwn[off] = (sun[tid] - STEP * ynf) * wd;
        ywn[off] = ynf * wd;
        if (tid == 0) vwn[n] = svn * wd;
    }
}

__global__ void k_final(const float* __restrict__ x0, float* __restrict__ out,
                        int ND, int last_idx, float comm) {
    int i = blockIdx.x * blockDim.x + threadIdx.x;
    if (i < ND) out[i] = x0[i];
    if (i == 0) out[last_idx] = comm;
}

// ---------------- host launcher ----------------

extern "C" void kernel_launch(void* const* d_in, const int* in_sizes, int n_in,
                              void* d_out, int out_size, void* d_ws, size_t ws_size,
                              hipStream_t stream) {
    const float* A  = (const float*)d_in[0];
    const float* b  = (const float*)d_in[1];
    const float* x  = (const float*)d_in[2];
    const int*   ei = (const int*)d_in[3];

    const int N = in_sizes[1] / D;        // b is [N, D]
    const int E = in_sizes[3] / 2;        // edge_index is [2, E]
    const size_t ND = (size_t)N * D;

    float* ws = (float*)d_ws;
    float* x0   = ws;
    float* uw0  = x0 + ND;
    float* yw0  = uw0 + ND;
    float* uw1  = yw0 + ND;
    float* yw1  = uw1 + ND;
    float* vw0  = yw1 + ND;
    float* vw1  = vw0 + N;
    float* invdeg = vw1 + N;
    float* degf = invdeg + N;
    int* degd    = (int*)(degf + N);
    int* row_ptr = degd + N;
    int* cursor  = row_ptr + N + 1;
    int* col     = cursor + N;

    k_setup<<<(N + 255) / 256, 256, 0, stream>>>(degf, degd, N);
    k_deg2<<<(E + 255) / 256, 256, 0, stream>>>(ei, degf, degd, E);
    k_scan<<<1, 1024, 0, stream>>>(degd, degf, row_ptr, cursor, invdeg, N, E);
    k_scatter<<<(E + 255) / 256, 256, 0, stream>>>(ei, cursor, col, E);
    k_init_grad<<<N, 256, 0, stream>>>(A, b, x, invdeg, uw0, yw0, vw0, x0, N);

    float *uc = uw0, *un = uw1, *yc = yw0, *yn = yw1, *vc = vw0, *vn = vw1;
    for (int l = 0; l < NUM_LAYERS; ++l) {
        k_layer<<<N, 256, 0, stream>>>(A, row_ptr, col, uc, yc, vc, invdeg,
                                       un, yn, vn, x0, N);
        float* t;
        t = uc; uc = un; un = t;
        t = yc; yc = yn; yn = t;
        t = vc; vc = vn; vn = t;
    }

    float comm = (float)(3 * NUM_LAYERS * E);
    k_final<<<((int)ND + 255) / 256, 256, 0, stream>>>(x0, (float*)d_out, (int)ND,
                                                       out_size - 1, comm);
}

// Round 3
// 1045.313 us; speedup vs baseline: 6.5430x; 1.4383x over previous
//
#include <hip/hip_runtime.h>
#include <hip/hip_bf16.h>
#include <hip/hip_fp16.h>

#define STEP 0.01f
#define D 64
#define NUM_LAYERS 10

union H8 { uint4 u; __half h[8]; };

__device__ inline void add4(float4& a, const float4 b) {
    a.x += b.x; a.y += b.y; a.z += b.z; a.w += b.w;
}

// ---------------- CSR build ----------------

__global__ void k_setup(float* __restrict__ degf, int* __restrict__ degd, int N) {
    int n = blockIdx.x * blockDim.x + threadIdx.x;
    if (n < N) { degf[n] = 1.0f; degd[n] = 0; }
}

__global__ void k_deg2(const int* __restrict__ ei, float* __restrict__ degf,
                       int* __restrict__ degd, int E) {
    int e = blockIdx.x * blockDim.x + threadIdx.x;
    if (e < E) {
        unsafeAtomicAdd(&degf[ei[e]], 1.0f);   // out-degree (src)
        atomicAdd(&degd[ei[E + e]], 1);        // in-degree (dst)
    }
}

__global__ __launch_bounds__(1024) void k_scan(
        const int* __restrict__ degd, const float* __restrict__ degf,
        int* __restrict__ row_ptr, int* __restrict__ cursor,
        float* __restrict__ invdeg, int N, int E) {
    __shared__ int part[1024];
    int tid = threadIdx.x;
    int chunk = (N + 1023) / 1024;
    int lo = tid * chunk, hi = min(lo + chunk, N);
    int s = 0;
    for (int i = lo; i < hi; ++i) s += degd[i];
    part[tid] = s;
    __syncthreads();
    for (int off = 1; off < 1024; off <<= 1) {
        int v = (tid >= off) ? part[tid - off] : 0;
        __syncthreads();
        part[tid] += v;
        __syncthreads();
    }
    int base = (tid == 0) ? 0 : part[tid - 1];
    for (int i = lo; i < hi; ++i) {
        row_ptr[i] = base;
        cursor[i] = base;
        base += degd[i];
        invdeg[i] = 1.0f / degf[i];
    }
    if (tid == 1023) row_ptr[N] = E;
}

__global__ void k_scatter(const int* __restrict__ ei, int* __restrict__ cursor,
                          int* __restrict__ col, int E) {
    int e = blockIdx.x * blockDim.x + threadIdx.x;
    if (e < E) {
        int pos = atomicAdd(&cursor[ei[E + e]], 1);
        col[pos] = ei[e];
    }
}

// ---------------- init: convert A->fp16 + y=2Ax+b + emit pre-weighted ----------------

__global__ __launch_bounds__(256) void k_init(
        const float* __restrict__ A, const float* __restrict__ b,
        const float* __restrict__ x, const float* __restrict__ invdeg,
        __half* __restrict__ Ah, float* __restrict__ uw, float* __restrict__ yw,
        float* __restrict__ vw, float* __restrict__ x0, int N) {
    __shared__ __align__(16) float sx[D];
    __shared__ float sy[D];
    int n = blockIdx.x, t = threadIdx.x;
    if (t < D) sx[t] = x[(size_t)n * D + t];
    __syncthreads();
    const float4* Af = (const float4*)(A + (size_t)n * D * D);
    int r = t >> 2, q = t & 3;
    float p = 0.0f;
    H8 pk0, pk1;
#pragma unroll
    for (int k = 0; k < 4; ++k) {
        float4 a = Af[t * 4 + k];
        int c = q * 16 + k * 4;
        p += a.x * sx[c] + a.y * sx[c + 1] + a.z * sx[c + 2] + a.w * sx[c + 3];
        __half* dh = ((k < 2) ? pk0.h : pk1.h) + (k & 1) * 4;
        dh[0] = __float2half(a.x);
        dh[1] = __float2half(a.y);
        dh[2] = __float2half(a.z);
        dh[3] = __float2half(a.w);
    }
    uint4* Aho = (uint4*)(Ah + (size_t)n * D * D);
    Aho[t * 2 + 0] = pk0.u;
    Aho[t * 2 + 1] = pk1.u;
    p += __shfl_xor(p, 1);
    p += __shfl_xor(p, 2);
    if (q == 0) sy[r] = 2.0f * p + b[(size_t)n * D + r];
    __syncthreads();
    if (t < D) {
        size_t off = (size_t)n * D + t;
        float wd = invdeg[n];
        float xv = sx[t];
        float yv = sy[t];
        uw[off] = (xv - STEP * yv) * wd;
        yw[off] = yv * wd;
        x0[off] = xv;
        if (t == 0) vw[n] = wd;
    }
}

// ---------------- fused layer ----------------

__global__ __launch_bounds__(256) void k_layer(
        const __half* __restrict__ Ah,
        const int* __restrict__ row_ptr, const int* __restrict__ col,
        const float* __restrict__ uw, const float* __restrict__ yw,
        const float* __restrict__ vw, const float* __restrict__ invdeg,
        float* __restrict__ uwn, float* __restrict__ ywn, float* __restrict__ vwn,
        float* __restrict__ x0, int N) {
    __shared__ __align__(16) float su[4][D];
    __shared__ __align__(16) float sy[4][D];
    __shared__ float sv[4];
    __shared__ __align__(16) float sdx[D];
    __shared__ float sun[D];
    __shared__ float sytot[D];
    __shared__ float syn[D];
    __shared__ float svn;

    int n = blockIdx.x, t = threadIdx.x;
    int lane = t & 63, w = t >> 6;
    int j = lane >> 4, q4 = lane & 15;

    // phase 1: gather — 4 edges per wave-pass, float4 per lane
    int rs = row_ptr[n], re = row_ptr[n + 1];
    float4 au = {0.f, 0.f, 0.f, 0.f}, ay = {0.f, 0.f, 0.f, 0.f};
    float av = 0.0f;
    for (int base = rs + w * 4; base < re; base += 16) {
        int e = base + j;
        if (e < re) {
            int s = col[e];
            float4 uu = ((const float4*)(uw + (size_t)s * D))[q4];
            float4 yy = ((const float4*)(yw + (size_t)s * D))[q4];
            add4(au, uu);
            add4(ay, yy);
            if (q4 == 0) av += vw[s];
        }
    }
    // reduce across the 4 edge slots (lanes xor 16, 32)
    au.x += __shfl_xor(au.x, 16); au.y += __shfl_xor(au.y, 16);
    au.z += __shfl_xor(au.z, 16); au.w += __shfl_xor(au.w, 16);
    au.x += __shfl_xor(au.x, 32); au.y += __shfl_xor(au.y, 32);
    au.z += __shfl_xor(au.z, 32); au.w += __shfl_xor(au.w, 32);
    ay.x += __shfl_xor(ay.x, 16); ay.y += __shfl_xor(ay.y, 16);
    ay.z += __shfl_xor(ay.z, 16); ay.w += __shfl_xor(ay.w, 16);
    ay.x += __shfl_xor(ay.x, 32); ay.y += __shfl_xor(ay.y, 32);
    ay.z += __shfl_xor(ay.z, 32); ay.w += __shfl_xor(ay.w, 32);
    av += __shfl_xor(av, 16);
    av += __shfl_xor(av, 32);
    if (j == 0) {
        ((float4*)su[w])[q4] = au;
        ((float4*)sy[w])[q4] = ay;
        if (q4 == 0) sv[w] = av;
    }
    __syncthreads();

    // phase 2: combine + self term; x1 = un/vn; dx = x1 - x0
    if (w == 0) {
        size_t off = (size_t)n * D + lane;
        float ut = su[0][lane] + su[1][lane] + su[2][lane] + su[3][lane] + uw[off];
        float yt = sy[0][lane] + sy[1][lane] + sy[2][lane] + sy[3][lane] + yw[off];
        float vt = sv[0] + sv[1] + sv[2] + sv[3] + vw[n];
        float x1 = ut / vt;
        sdx[lane] = x1 - x0[off];
        x0[off] = x1;
        sun[lane] = ut;
        sytot[lane] = yt;
        if (lane == 0) svn = vt;
    }
    __syncthreads();

    // phase 3: yn = yt + 2*A@dx  (fp16 A, f32 accumulate)
    {
        const uint4* Ahp = (const uint4*)(Ah + (size_t)n * D * D);
        int r = t >> 2, q = t & 3;
        float p = 0.0f;
#pragma unroll
        for (int k = 0; k < 2; ++k) {
            H8 a;
            a.u = Ahp[t * 2 + k];
            int c = q * 16 + k * 8;
#pragma unroll
            for (int jj = 0; jj < 8; ++jj)
                p += __half2float(a.h[jj]) * sdx[c + jj];
        }
        p += __shfl_xor(p, 1);
        p += __shfl_xor(p, 2);
        if (q == 0) syn[r] = sytot[r] + 2.0f * p;
    }
    __syncthreads();

    // phase 4: emit next layer's pre-weighted messages
    if (t < D) {
        float wd = invdeg[n];
        float ynf = syn[t];
        size_t off = (size_t)n * D + t;
        uwn[off] = (sun[t] - STEP * ynf) * wd;
        ywn[off] = ynf * wd;
        if (t == 0) vwn[n] = svn * wd;
    }
}

__global__ void k_final(const float* __restrict__ x0, float* __restrict__ out,
                        int ND, int last_idx, float comm) {
    int i = blockIdx.x * blockDim.x + threadIdx.x;
    if (i < ND) out[i] = x0[i];
    if (i == 0) out[last_idx] = comm;
}

// ---------------- host launcher ----------------

extern "C" void kernel_launch(void* const* d_in, const int* in_sizes, int n_in,
                              void* d_out, int out_size, void* d_ws, size_t ws_size,
                              hipStream_t stream) {
    const float* A  = (const float*)d_in[0];
    const float* b  = (const float*)d_in[1];
    const float* x  = (const float*)d_in[2];
    const int*   ei = (const int*)d_in[3];

    const int N = in_sizes[1] / D;        // b is [N, D]
    const int E = in_sizes[3] / 2;        // edge_index is [2, E]
    const size_t ND = (size_t)N * D;

    char* ws = (char*)d_ws;
    __half* Ah = (__half*)ws;                    // N*D*D halves (16B aligned)
    float* x0   = (float*)(ws + ND * D * sizeof(__half));
    float* uw0  = x0 + ND;
    float* yw0  = uw0 + ND;
    float* uw1  = yw0 + ND;
    float* yw1  = uw1 + ND;
    float* vw0  = yw1 + ND;
    float* vw1  = vw0 + N;
    float* invdeg = vw1 + N;
    float* degf = invdeg + N;
    int* degd    = (int*)(degf + N);
    int* row_ptr = degd + N;
    int* cursor  = row_ptr + N + 4;   // padded for alignment
    int* col     = cursor + N;

    k_setup<<<(N + 255) / 256, 256, 0, stream>>>(degf, degd, N);
    k_deg2<<<(E + 255) / 256, 256, 0, stream>>>(ei, degf, degd, E);
    k_scan<<<1, 1024, 0, stream>>>(degd, degf, row_ptr, cursor, invdeg, N, E);
    k_scatter<<<(E + 255) / 256, 256, 0, stream>>>(ei, cursor, col, E);
    k_init<<<N, 256, 0, stream>>>(A, b, x, invdeg, Ah, uw0, yw0, vw0, x0, N);

    float *uc = uw0, *un = uw1, *yc = yw0, *yn = yw1, *vc = vw0, *vn = vw1;
    for (int l = 0; l < NUM_LAYERS; ++l) {
        k_layer<<<N, 256, 0, stream>>>(Ah, row_ptr, col, uc, yc, vc, invdeg,
                                       un, yn, vn, x0, N);
        float* t;
        t = uc; uc = un; un = t;
        t = yc; yc = yn; yn = t;
        t = vc; vc = vn; vn = t;
    }

    float comm = (float)(3 * NUM_LAYERS * E);
    k_final<<<((int)ND + 255) / 256, 256, 0, stream>>>(x0, (float*)d_out, (int)ND,
                                                       out_size - 1, comm);
}

// Round 4
// 964.324 us; speedup vs baseline: 7.0925x; 1.0840x over previous
//
#include <hip/hip_runtime.h>
#include <hip/hip_bf16.h>
#include <hip/hip_fp16.h>

#define STEP 0.01f
#define D 64
#define NUM_LAYERS 10

union H4 { uint2 u; __half h[4]; };
union H8 { uint4 u; __half2 h2[4]; __half h[8]; };

// ---------------- CSR build ----------------

__global__ void k_setup(float* __restrict__ degf, int* __restrict__ degd, int N) {
    int n = blockIdx.x * blockDim.x + threadIdx.x;
    if (n < N) { degf[n] = 1.0f; degd[n] = 0; }
}

__global__ void k_deg2(const int* __restrict__ ei, float* __restrict__ degf,
                       int* __restrict__ degd, int E) {
    int e = blockIdx.x * blockDim.x + threadIdx.x;
    if (e < E) {
        unsafeAtomicAdd(&degf[ei[e]], 1.0f);   // out-degree (src)
        atomicAdd(&degd[ei[E + e]], 1);        // in-degree (dst)
    }
}

__global__ __launch_bounds__(1024) void k_scan(
        const int* __restrict__ degd, const float* __restrict__ degf,
        int* __restrict__ row_ptr, int* __restrict__ cursor,
        float* __restrict__ invdeg, int N, int E) {
    __shared__ int part[1024];
    int tid = threadIdx.x;
    int chunk = (N + 1023) / 1024;
    int lo = tid * chunk, hi = min(lo + chunk, N);
    int s = 0;
    for (int i = lo; i < hi; ++i) s += degd[i];
    part[tid] = s;
    __syncthreads();
    for (int off = 1; off < 1024; off <<= 1) {
        int v = (tid >= off) ? part[tid - off] : 0;
        __syncthreads();
        part[tid] += v;
        __syncthreads();
    }
    int base = (tid == 0) ? 0 : part[tid - 1];
    for (int i = lo; i < hi; ++i) {
        row_ptr[i] = base;
        cursor[i] = base;
        base += degd[i];
        invdeg[i] = 1.0f / degf[i];
    }
    if (tid == 1023) row_ptr[N] = E;
}

__global__ void k_scatter(const int* __restrict__ ei, int* __restrict__ cursor,
                          int* __restrict__ col, int E) {
    int e = blockIdx.x * blockDim.x + threadIdx.x;
    if (e < E) {
        int pos = atomicAdd(&cursor[ei[E + e]], 1);
        col[pos] = ei[e];
    }
}

// ---------------- init: A->fp16 + y=2Ax+b + emit pre-weighted fp16 msgs ----------------

__global__ __launch_bounds__(256) void k_init(
        const float* __restrict__ A, const float* __restrict__ b,
        const float* __restrict__ x, const float* __restrict__ invdeg,
        __half* __restrict__ Ah, __half2* __restrict__ msg,
        float* __restrict__ vw, float* __restrict__ x0, int N) {
    __shared__ __align__(16) float sx[D];
    __shared__ float syv[D];
    int n = blockIdx.x, t = threadIdx.x;
    int lane = t & 63, w = t >> 6, colgrp = lane & 15;
    if (t < D) sx[t] = x[(size_t)n * D + t];
    __syncthreads();
    const float* An = A + (size_t)n * D * D;
    __half* Ahn = Ah + (size_t)n * D * D;
    float4 xr = ((const float4*)sx)[colgrp];
    int rbase = w * 16 + (lane >> 4);
#pragma unroll
    for (int g = 0; g < 4; ++g) {
        int row = rbase + g * 4;
        float4 a = ((const float4*)(An + (size_t)row * D))[colgrp];
        H4 pk;
        pk.h[0] = __float2half(a.x);
        pk.h[1] = __float2half(a.y);
        pk.h[2] = __float2half(a.z);
        pk.h[3] = __float2half(a.w);
        ((uint2*)(Ahn + (size_t)row * D))[colgrp] = pk.u;
        float p = a.x * xr.x + a.y * xr.y + a.z * xr.z + a.w * xr.w;
        p += __shfl_xor(p, 1);
        p += __shfl_xor(p, 2);
        p += __shfl_xor(p, 4);
        p += __shfl_xor(p, 8);
        if (colgrp == 0) syv[row] = 2.0f * p + b[(size_t)n * D + row];
    }
    __syncthreads();
    if (t < D) {
        float wd = invdeg[n];
        float xv = sx[t];
        float yv = syv[t];
        msg[(size_t)n * D + t] = __floats2half2_rn((xv - STEP * yv) * wd, yv * wd);
        x0[(size_t)n * D + t] = xv;
        if (t == 0) vw[n] = wd;
    }
}

// ---------------- fused layer ----------------

__global__ __launch_bounds__(256) void k_layer(
        const __half* __restrict__ Ah,
        const int* __restrict__ row_ptr, const int* __restrict__ col,
        const __half2* __restrict__ msg, const float* __restrict__ vw,
        const float* __restrict__ invdeg,
        __half2* __restrict__ msgn, float* __restrict__ vwn,
        float* __restrict__ x0, float* __restrict__ xout,
        int last_idx, float comm, int N) {
    __shared__ float su[4][D];
    __shared__ float sy[4][D];
    __shared__ float sv[4];
    __shared__ __align__(16) float sdx[D];
    __shared__ float sun[D];
    __shared__ float sytot[D];
    __shared__ float syn[D];
    __shared__ float svn;

    int n = blockIdx.x, t = threadIdx.x;
    int lane = t & 63, w = t >> 6;
    int j = lane >> 4, q4 = lane & 15;

    // phase 1: gather — 4 edges per wave-pass, one uint4 (4x half2 (u,y)) per lane
    int rs = row_ptr[n], re = row_ptr[n + 1];
    float4 au = {0.f, 0.f, 0.f, 0.f}, ay = {0.f, 0.f, 0.f, 0.f};
    float av = 0.0f;
    for (int base = rs + w * 4; base < re; base += 16) {
        int e = base + j;
        if (e < re) {
            int s = col[e];
            H8 m;
            m.u = ((const uint4*)(msg + (size_t)s * D))[q4];
            float2 f0 = __half22float2(m.h2[0]);
            float2 f1 = __half22float2(m.h2[1]);
            float2 f2 = __half22float2(m.h2[2]);
            float2 f3 = __half22float2(m.h2[3]);
            au.x += f0.x; ay.x += f0.y;
            au.y += f1.x; ay.y += f1.y;
            au.z += f2.x; ay.z += f2.y;
            au.w += f3.x; ay.w += f3.y;
            if (q4 == 0) av += vw[s];
        }
    }
    // reduce across the 4 edge slots (lanes xor 16, 32)
    au.x += __shfl_xor(au.x, 16); au.y += __shfl_xor(au.y, 16);
    au.z += __shfl_xor(au.z, 16); au.w += __shfl_xor(au.w, 16);
    au.x += __shfl_xor(au.x, 32); au.y += __shfl_xor(au.y, 32);
    au.z += __shfl_xor(au.z, 32); au.w += __shfl_xor(au.w, 32);
    ay.x += __shfl_xor(ay.x, 16); ay.y += __shfl_xor(ay.y, 16);
    ay.z += __shfl_xor(ay.z, 16); ay.w += __shfl_xor(ay.w, 16);
    ay.x += __shfl_xor(ay.x, 32); ay.y += __shfl_xor(ay.y, 32);
    ay.z += __shfl_xor(ay.z, 32); ay.w += __shfl_xor(ay.w, 32);
    av += __shfl_xor(av, 16);
    av += __shfl_xor(av, 32);
    if (j == 0) {
        ((float4*)su[w])[q4] = au;
        ((float4*)sy[w])[q4] = ay;
        if (q4 == 0) sv[w] = av;
    }
    __syncthreads();

    // phase 2: combine + self term; x1 = un/vn; dx = x1 - x0
    if (w == 0) {
        size_t off = (size_t)n * D + lane;
        float2 self = __half22float2(msg[off]);
        float ut = su[0][lane] + su[1][lane] + su[2][lane] + su[3][lane] + self.x;
        float yt = sy[0][lane] + sy[1][lane] + sy[2][lane] + sy[3][lane] + self.y;
        float vt = sv[0] + sv[1] + sv[2] + sv[3] + vw[n];
        float x1 = ut / vt;
        sdx[lane] = x1 - x0[off];
        x0[off] = x1;
        if (xout) xout[off] = x1;
        sun[lane] = ut;
        sytot[lane] = yt;
        if (lane == 0) svn = vt;
    }
    __syncthreads();

    // phase 3: yn = yt + 2*A@dx  (fp16 A, fully-coalesced 1KB wave loads)
    {
        const uint4* Ahp = (const uint4*)(Ah + (size_t)n * D * D);
        int cb = (t & 7) * 8;
        int r0 = t >> 3;
        H8 a0, a1;
        a0.u = Ahp[t];
        a1.u = Ahp[256 + t];
        float p0 = 0.0f, p1 = 0.0f;
#pragma unroll
        for (int jj = 0; jj < 8; ++jj) {
            float dv = sdx[cb + jj];
            p0 += __half2float(a0.h[jj]) * dv;
            p1 += __half2float(a1.h[jj]) * dv;
        }
        p0 += __shfl_xor(p0, 1); p1 += __shfl_xor(p1, 1);
        p0 += __shfl_xor(p0, 2); p1 += __shfl_xor(p1, 2);
        p0 += __shfl_xor(p0, 4); p1 += __shfl_xor(p1, 4);
        if ((lane & 7) == 0) {
            syn[r0]      = sytot[r0]      + 2.0f * p0;
            syn[32 + r0] = sytot[32 + r0] + 2.0f * p1;
        }
    }
    __syncthreads();

    // phase 4: emit next layer's pre-weighted fp16 messages
    if (t < D) {
        float wd = invdeg[n];
        float ynf = syn[t];
        msgn[(size_t)n * D + t] = __floats2half2_rn((sun[t] - STEP * ynf) * wd, ynf * wd);
        if (t == 0) vwn[n] = svn * wd;
    }
    if (xout && n == 0 && t == 0) xout[last_idx] = comm;
}

// ---------------- host launcher ----------------

extern "C" void kernel_launch(void* const* d_in, const int* in_sizes, int n_in,
                              void* d_out, int out_size, void* d_ws, size_t ws_size,
                              hipStream_t stream) {
    const float* A  = (const float*)d_in[0];
    const float* b  = (const float*)d_in[1];
    const float* x  = (const float*)d_in[2];
    const int*   ei = (const int*)d_in[3];

    const int N = in_sizes[1] / D;        // b is [N, D]
    const int E = in_sizes[3] / 2;        // edge_index is [2, E]
    const size_t ND = (size_t)N * D;

    char* ws = (char*)d_ws;
    __half* Ah = (__half*)ws;                               // N*D*D halves
    __half2* msg0 = (__half2*)(ws + ND * D * sizeof(__half));
    __half2* msg1 = msg0 + ND;
    float* x0   = (float*)(msg1 + ND);
    float* vw0  = x0 + ND;
    float* vw1  = vw0 + N;
    float* invdeg = vw1 + N;
    float* degf = invdeg + N;
    int* degd    = (int*)(degf + N);
    int* row_ptr = degd + N;
    int* cursor  = row_ptr + N + 4;
    int* col     = cursor + N;

    k_setup<<<(N + 255) / 256, 256, 0, stream>>>(degf, degd, N);
    k_deg2<<<(E + 255) / 256, 256, 0, stream>>>(ei, degf, degd, E);
    k_scan<<<1, 1024, 0, stream>>>(degd, degf, row_ptr, cursor, invdeg, N, E);
    k_scatter<<<(E + 255) / 256, 256, 0, stream>>>(ei, cursor, col, E);
    k_init<<<N, 256, 0, stream>>>(A, b, x, invdeg, Ah, msg0, vw0, x0, N);

    float comm = (float)(3 * NUM_LAYERS * E);
    __half2 *mc = msg0, *mn = msg1;
    float *vc = vw0, *vn = vw1;
    for (int l = 0; l < NUM_LAYERS; ++l) {
        float* xout = (l == NUM_LAYERS - 1) ? (float*)d_out : nullptr;
        k_layer<<<N, 256, 0, stream>>>(Ah, row_ptr, col, mc, vc, invdeg,
                                       mn, vn, x0, xout, out_size - 1, comm, N);
        __half2* tm = mc; mc = mn; mn = tm;
        float* tv = vc; vc = vn; vn = tv;
    }
}